// Round 9
// baseline (258.642 us; speedup 1.0000x reference)
//
#include <hip/hip_runtime.h>

#define D_MODEL 1024
#define N_HEADS 16
#define DK 64
#define BATCH 4
#define SEQ 2048
#define MROWS (BATCH * SEQ)   // 8192
#define TILE_E (256 * 64)     // u16 elems in one 256x64 bf16 LDS tile (32 KiB)

typedef float f32x4 __attribute__((ext_vector_type(4)));
typedef short bf16x8 __attribute__((ext_vector_type(8)));
typedef unsigned short u16;
typedef unsigned short u16x8 __attribute__((ext_vector_type(8)));

__device__ __forceinline__ float bf2f(u16 u) {
    union { unsigned int i; float f; } v; v.i = ((unsigned int)u) << 16; return v.f;
}
__device__ __forceinline__ u16 f2bf(float f) {
    union { float f; unsigned int i; } v; v.f = f;
    unsigned int u = v.i;
    u += 0x7fffu + ((u >> 16) & 1u);  // RNE
    return (u16)(u >> 16);
}
// pack two fp32 -> two bf16 (round-half-up) in ONE v_perm: low u16 = a, high = b
__device__ __forceinline__ unsigned int pk2(float a, float b) {
    union { float f; unsigned int i; } ua, ub; ua.f = a; ub.f = b;
    return __builtin_amdgcn_perm(ub.i + 0x8000u, ua.i + 0x8000u, 0x07060302u);
}
// pack two fp32 -> two bf16 (RNE) in one HW instr (T12)
__device__ __forceinline__ unsigned int cvtpk(float a, float b) {
    unsigned int r;
    asm("v_cvt_pk_bf16_f32 %0, %1, %2" : "=v"(r) : "v"(a), "v"(b));
    return r;
}

// async global->LDS, 16B per lane; LDS dest = wave-uniform base + lane*16
typedef unsigned int u32_as1 __attribute__((address_space(1)));
typedef unsigned int u32_as3 __attribute__((address_space(3)));
__device__ __forceinline__ void gload16(const u16* g, u16* l) {
    __builtin_amdgcn_global_load_lds((const u32_as1*)g, (u32_as3*)l, 16, 0, 0);
}

// ---------------- fused fp32 -> bf16 conversion (all 7 tensors, 8 elems/thread) ----
__global__ __launch_bounds__(256) void convert_all(
    const float* __restrict__ x, const float* __restrict__ pe,
    const float* __restrict__ w0, const float* __restrict__ w1, const float* __restrict__ w2,
    const float* __restrict__ w3, const float* __restrict__ w4,
    u16* __restrict__ xb, u16* __restrict__ pb,
    u16* __restrict__ wb0, u16* __restrict__ wb1, u16* __restrict__ wb2,
    u16* __restrict__ wb3, u16* __restrict__ wb4)
{
    int t = blockIdx.x * 256 + threadIdx.x;   // unit = 8 elems
    const float* src; u16* dst; int idx;
    if (t < 1048576)      { src = x;  dst = xb; idx = t; }
    else if (t < 1310720) { src = pe; dst = pb; idx = t - 1048576; }
    else {
        int r = t - 1310720; int w = r >> 17; idx = r & 131071;
        if      (w == 0) { src = w0; dst = wb0; }
        else if (w == 1) { src = w1; dst = wb1; }
        else if (w == 2) { src = w2; dst = wb2; }
        else if (w == 3) { src = w3; dst = wb3; }
        else             { src = w4; dst = wb4; }
    }
    const float4* p = (const float4*)src + (size_t)idx * 2;
    float4 a = p[0], b = p[1];
    u16x8 o;
    o[0] = f2bf(a.x); o[1] = f2bf(a.y); o[2] = f2bf(a.z); o[3] = f2bf(a.w);
    o[4] = f2bf(b.x); o[5] = f2bf(b.y); o[6] = f2bf(b.z); o[7] = f2bf(b.w);
    *((u16x8*)dst + idx) = o;
}

// ===========================================================================
// 256x256 / BK=64 / 8-wave / 8-phase GEMM core (T2+T3+T4+T5, m201 template).
// K = 1024 fixed (NT = 16 tiles of 64). See round-1 comments for the stage
// stream / counted-vmcnt design; unchanged this round.
// ===========================================================================
#define SA(bufp, h, kk) do { \
    gload16(Ag + (size_t)((h) * 64) * 1024 + (kk),       (bufp) + ((h) * 64 + wv * 8) * 64); \
    gload16(Ag + (size_t)((h) * 64 + 128) * 1024 + (kk), (bufp) + ((h) * 64 + 128 + wv * 8) * 64); \
} while (0)
#define SB(bufp, h, kk) do { \
    gload16(Wg + (size_t)((h) * 32) * 1024 + (kk),       (bufp) + (wq2 * 64 + (h) * 32 + w3 * 8) * 64); \
    gload16(Wg + (size_t)((h) * 32 + 128) * 1024 + (kk), (bufp) + (128 + wq2 * 64 + (h) * 32 + w3 * 8) * 64); \
} while (0)
#define LOAD_A(mh) \
    _Pragma("unroll") \
    for (int mi = 0; mi < 4; ++mi) { \
        aA[mi][0] = *(const bf16x8*)&Abuf[aoff0 + ((mh) * 64 + mi * 16) * 64]; \
        aA[mi][1] = *(const bf16x8*)&Abuf[aoff1 + ((mh) * 64 + mi * 16) * 64]; \
    }
#define LOAD_B(nh) \
    _Pragma("unroll") \
    for (int ni = 0; ni < 2; ++ni) { \
        bB[nh][ni][0] = *(const bf16x8*)&Bbuf[boff0 + ((nh) * 32 + ni * 16) * 64]; \
        bB[nh][ni][1] = *(const bf16x8*)&Bbuf[boff1 + ((nh) * 32 + ni * 16) * 64]; \
    }
#define MFMA16(mh, nh) \
    _Pragma("unroll") \
    for (int ks = 0; ks < 2; ++ks) \
        _Pragma("unroll") \
        for (int mi = 0; mi < 4; ++mi) \
            _Pragma("unroll") \
            for (int ni = 0; ni < 2; ++ni) \
                acc[(mh) * 4 + mi][(nh) * 2 + ni] = __builtin_amdgcn_mfma_f32_16x16x32_bf16( \
                    aA[mi][ks], bB[nh][ni][ks], acc[(mh) * 4 + mi][(nh) * 2 + ni], 0, 0, 0);

__device__ __forceinline__ void gemm256_loop(
    const u16* __restrict__ Ag, const u16* __restrict__ Wg,
    u16* AsBase, u16* BsBase, int wv,
    int aoff0, int aoff1, int boff0, int boff1, f32x4 (&acc)[8][4])
{
    const int wq2 = wv >> 2, w3 = wv & 3;
    bf16x8 aA[4][2], bB[2][2][2];

    // prologue: tile0 {Ah0,Bh0,Bh1,Ah1} + tile1 {Ah0,Bh0,Ah1}  (14 loads)
    SA(AsBase, 0, 0); SB(BsBase, 0, 0); SB(BsBase, 1, 0); SA(AsBase, 1, 0);
    SA(AsBase + TILE_E, 0, 64); SB(BsBase + TILE_E, 0, 64); SA(AsBase + TILE_E, 1, 64);
    asm volatile("s_waitcnt vmcnt(6)" ::: "memory");   // tile0 resident, 3 halves in flight
    __builtin_amdgcn_s_barrier();

    for (int T = 0; T < 16; ++T) {
        u16* Abuf = AsBase + (T & 1) * TILE_E;
        u16* Bbuf = BsBase + (T & 1) * TILE_E;
        u16* Both = BsBase + ((T & 1) ^ 1) * TILE_E;
        const int k2 = T * 64 + 128;

        // ---- phase 1: (mh=0, nh=0)
        LOAD_A(0); LOAD_B(0);
        if (T < 15) SB(Both, 1, T * 64 + 64);          // Bh1(T+1)
        __builtin_amdgcn_s_barrier();
        asm volatile("s_waitcnt lgkmcnt(0)" ::: "memory");
        __builtin_amdgcn_s_setprio(1); MFMA16(0, 0); __builtin_amdgcn_s_setprio(0);
        __builtin_amdgcn_s_barrier();

        // ---- phase 2: (0,1)
        LOAD_B(1);
        if (T < 14) SA(Abuf, 0, k2);                   // Ah0(T+2) over consumed region
        __builtin_amdgcn_s_barrier();
        asm volatile("s_waitcnt lgkmcnt(0)" ::: "memory");
        __builtin_amdgcn_s_setprio(1); MFMA16(0, 1); __builtin_amdgcn_s_setprio(0);
        __builtin_amdgcn_s_barrier();

        // ---- phase 3: (1,0)
        LOAD_A(1);
        if (T < 14) SB(Bbuf, 0, k2);                   // Bh0(T+2)
        __builtin_amdgcn_s_barrier();
        asm volatile("s_waitcnt lgkmcnt(0)" ::: "memory");
        __builtin_amdgcn_s_setprio(1); MFMA16(1, 0); __builtin_amdgcn_s_setprio(0);
        __builtin_amdgcn_s_barrier();

        // ---- phase 4: (1,1), counted wait for next tile (never vmcnt 0 mid-loop)
        if (T < 14) SA(Abuf, 1, k2);                   // Ah1(T+2)
        __builtin_amdgcn_s_barrier();
        __builtin_amdgcn_s_setprio(1); MFMA16(1, 1); __builtin_amdgcn_s_setprio(0);
        if (T < 14)      { asm volatile("s_waitcnt vmcnt(6)" ::: "memory"); }
        else if (T < 15) { asm volatile("s_waitcnt vmcnt(0)" ::: "memory"); }
        __builtin_amdgcn_s_barrier();
    }
}

// ---------------- fused QKVP GEMM: 416 blocks --------------------------------------
// THIS ROUND: m-major-per-XCD mapping. XCD x owns m-tiles {4x..4x+3} for all
// 12 (chunk,n) groups + 4 P-tiles: co-resident A working set = 2 MB (was 16 MB,
// thrashing the 4 MB L2) -> A-tile reads become L2 hits after the first panel;
// second machine-wave re-reads A already hot in its XCD's L2.
// Epilogue: Q/K/P bounce acc through LDS -> full-128B-line u16x8 stores.
__global__ __launch_bounds__(512, 1) void qkv_gemm256(
    const u16* __restrict__ xb, const u16* __restrict__ peb,
    const u16* __restrict__ wqb, const u16* __restrict__ wkb,
    const u16* __restrict__ wvb, const u16* __restrict__ wpb,
    const float* __restrict__ bq, const float* __restrict__ bk,
    const float* __restrict__ bv, const float* __restrict__ bp,
    u16* __restrict__ Qb, u16* __restrict__ Kb, u16* __restrict__ V3,
    u16* __restrict__ Pb)
{
    __shared__ __align__(16) u16 SH[4 * TILE_E];   // 128 KiB: As | Bs, reused by epilogue
    u16* As = SH;
    u16* Bs = SH + 2 * TILE_E;

    const int tid  = threadIdx.x;
    const int lane = tid & 63;
    const int wv   = tid >> 6;     // 0..7
    const int l15  = lane & 15;
    const int quad = lane >> 4;
    const int wm = wv >> 2, wn = wv & 3;

    // m-major-per-XCD mapping (bijective: 8 XCD x 52 idx = 416)
    const int xcd = blockIdx.x & 7;
    const int idx = blockIdx.x >> 3;          // 0..51
    int chunk, m0, n0;
    if (idx < 48) {
        int g = idx >> 2;                     // 0..11 = (chunk, nb)
        chunk = g >> 2; n0 = (g & 3) * 256;
        m0 = (xcd * 4 + (idx & 3)) * 256;     // XCD-contiguous m
    } else {
        int p = xcd * 4 + (idx - 48);         // 0..31
        chunk = 3; m0 = (p & 7) * 256; n0 = (p >> 3) * 256;
    }

    const u16* Abase = (chunk == 3) ? peb : xb;
    const u16* Wbase = (chunk == 0) ? wqb : ((chunk == 1) ? wkb : ((chunk == 2) ? wvb : wpb));

    // staging: per-thread global source with pre-applied column swizzle
    const int trow = tid >> 3;                             // 0..63
    const int swz  = ((tid & 7) ^ (trow & 7)) * 8;
    const u16* Ag = Abase + (size_t)(m0 + trow) * 1024 + swz;
    const u16* Wg = Wbase + (size_t)(n0 + (wv >> 2) * 64 + (trow & 31)) * 1024 + swz;

    // ds_read offsets with matching swizzle (row&7 == l15&7 for all frag rows)
    const int x7 = l15 & 7;
    const int aoff0 = (wm * 128 + l15) * 64 + ((quad    ) ^ x7) * 8;
    const int aoff1 = (wm * 128 + l15) * 64 + ((quad + 4) ^ x7) * 8;
    const int boff0 = (wn * 64 + l15) * 64 + ((quad    ) ^ x7) * 8;
    const int boff1 = (wn * 64 + l15) * 64 + ((quad + 4) ^ x7) * 8;

    f32x4 acc[8][4];
#pragma unroll
    for (int i = 0; i < 8; ++i)
#pragma unroll
        for (int j = 0; j < 4; ++j) acc[i][j] = f32x4{0.f, 0.f, 0.f, 0.f};

    gemm256_loop(Ag, Wg, As, Bs, wv, aoff0, aoff1, boff0, boff1, acc);

    // epilogue [m89 layout: C row = quad*4+r (+16m), col = l15 (+16n)]
    const float* bias = (chunk == 0) ? bq : ((chunk == 1) ? bk : ((chunk == 2) ? bv : bp));
    const int r0 = quad * 4;
    if (chunk == 2) {                            // V -> interleaved layout (128B/instr already)
#pragma unroll
        for (int n = 0; n < 4; ++n) {
            int col = n0 + wn * 64 + n * 16 + l15;
            float bvv = bias[col];
#pragma unroll
            for (int m = 0; m < 8; ++m) {
                int row0 = m0 + wm * 128 + m * 16 + r0;
                int hh = col >> 6, d = col & 63;
                int bb = row0 >> 11, sl = row0 & 2047;
                union { u16 h[4]; uint2 v; } pk;
#pragma unroll
                for (int r = 0; r < 4; ++r) pk.h[r] = f2bf(acc[m][n][r] + bvv);
                *((uint2*)V3 + ((size_t)(bb * 16 + hh) * 512 + (sl >> 2)) * 64 + d) = pk.v;
            }
        }
    } else {                                     // Q/K/P: LDS bounce -> full-line stores
        u16* dst = (chunk == 0) ? Qb : ((chunk == 1) ? Kb : Pb);
#pragma unroll
        for (int p = 0; p < 2; ++p) {
            __syncthreads();                     // prior pass reads / K-loop reads done
            if (wm == p) {                       // 4 waves own rows p*128..p*128+127
#pragma unroll
                for (int n = 0; n < 4; ++n) {
                    int colL = wn * 64 + n * 16 + l15;
                    float bvv = bias[n0 + colL];
#pragma unroll
                    for (int m = 0; m < 8; ++m) {
#pragma unroll
                        for (int r = 0; r < 4; ++r)
                            SH[(m * 16 + r0 + r) * 264 + colL] = f2bf(acc[m][n][r] + bvv);
                    }
                }
            }
            __syncthreads();
            // 512 threads, 8 lanes/row: each instr = 16 rows x 128B full lines
            const int rbase = m0 + p * 128;
#pragma unroll
            for (int s = 0; s < 2; ++s) {
                int rowL = (tid >> 3) + s * 64;
#pragma unroll
                for (int i = 0; i < 4; ++i) {
                    int cc = (tid & 7) + i * 8;          // 16B chunk 0..31
                    *(u16x8*)(dst + (size_t)(rbase + rowL) * 1024 + n0 + cc * 8) =
                        *(const u16x8*)&SH[rowL * 264 + cc * 8];
                }
            }
        }
    }
}

#undef SA
#undef SB
#undef LOAD_A
#undef LOAD_B
#undef MFMA16

// ---------------- output GEMM: out[8192,1024] = AO @ Wo^T + bo (fp32 out) ----------
// 8-phase counted-vmcnt core, 256m x 128n tile -> EXACTLY 256 blocks
// (one machine-wave, zero tail). 8 waves as 4m x 2n (wave-tile 64x64, acc[4][4]).
// Mapping already m-major-per-XCD (4 MB working set fits L2).
#define A_TILE (256 * 64)
#define B_TILE (128 * 64)
#define SAo(bufp, h, kk) do { \
    gload16(Ag + (size_t)((h) * 32) * 1024 + (kk),     (bufp) + (adst + (h) * 32) * 64); \
    gload16(Ag + (size_t)((h) * 32 + 8) * 1024 + (kk), (bufp) + (adst + (h) * 32 + 8) * 64); \
} while (0)
#define SBo(bufp, nh, kk) \
    gload16(Wg + (size_t)((nh) * 32) * 1024 + (kk), (bufp) + (bdst + (nh) * 32) * 64)
#define LAo(mh) \
    _Pragma("unroll") \
    for (int mi = 0; mi < 2; ++mi) { \
        aA[mi][0] = *(const bf16x8*)&Abuf[aoff0 + ((mh) * 32 + mi * 16) * 64]; \
        aA[mi][1] = *(const bf16x8*)&Abuf[aoff1 + ((mh) * 32 + mi * 16) * 64]; \
    }
#define LBo(nh) \
    _Pragma("unroll") \
    for (int ni = 0; ni < 2; ++ni) { \
        bB[nh][ni][0] = *(const bf16x8*)&Bbuf[boff0 + ((nh) * 32 + ni * 16) * 64]; \
        bB[nh][ni][1] = *(const bf16x8*)&Bbuf[boff1 + ((nh) * 32 + ni * 16) * 64]; \
    }
#define MMo(mh, nh) \
    _Pragma("unroll") \
    for (int ks = 0; ks < 2; ++ks) \
        _Pragma("unroll") \
        for (int mi = 0; mi < 2; ++mi) \
            _Pragma("unroll") \
            for (int ni = 0; ni < 2; ++ni) \
                acc[(mh) * 2 + mi][(nh) * 2 + ni] = __builtin_amdgcn_mfma_f32_16x16x32_bf16( \
                    aA[mi][ks], bB[nh][ni][ks], acc[(mh) * 2 + mi][(nh) * 2 + ni], 0, 0, 0);

__global__ __launch_bounds__(512, 2) void gemm_out256n(
    const u16* __restrict__ A, const u16* __restrict__ W,
    const float* __restrict__ bias, float* __restrict__ Cout)
{
    __shared__ __align__(16) u16 As[2 * A_TILE];   // 64 KiB
    __shared__ __align__(16) u16 Bs[2 * B_TILE];   // 32 KiB

    const int tid  = threadIdx.x;
    const int lane = tid & 63;
    const int wv   = tid >> 6;
    const int l15  = lane & 15;
    const int quad = lane >> 4;
    const int wm = wv >> 1, wn = wv & 1;   // 4m x 2n wave grid

    int wg = (blockIdx.x & 7) * 32 + (blockIdx.x >> 3);   // bijective XCD swizzle
    const int m0 = (wg >> 3) * 256;
    const int n0 = (wg & 7) * 128;

    // staging: per-thread global source with pre-applied column swizzle
    const int swz    = ((tid & 7) ^ ((tid >> 3) & 7)) * 8;
    const int arow_t = (wv >> 1) * 64 + (wv & 1) * 16 + (lane >> 3);
    const int brow_t = (wv >> 2) * 64 + (wv & 3) * 8 + (lane >> 3);
    const u16* Ag = A + (size_t)(m0 + arow_t) * 1024 + swz;
    const u16* Wg = W + (size_t)(n0 + brow_t) * 1024 + swz;
    const int adst = (wv >> 1) * 64 + (wv & 1) * 16;   // + h*32 (+8 for 2nd call)
    const int bdst = (wv >> 2) * 64 + (wv & 3) * 8;    // + nh*32

    const int x7 = l15 & 7;
    const int aoff0 = (wm * 64 + l15) * 64 + ((quad    ) ^ x7) * 8;
    const int aoff1 = (wm * 64 + l15) * 64 + ((quad + 4) ^ x7) * 8;
    const int boff0 = (wn * 64 + l15) * 64 + ((quad    ) ^ x7) * 8;
    const int boff1 = (wn * 64 + l15) * 64 + ((quad + 4) ^ x7) * 8;

    f32x4 acc[4][4];
#pragma unroll
    for (int i = 0; i < 4; ++i)
#pragma unroll
        for (int j = 0; j < 4; ++j) acc[i][j] = f32x4{0.f, 0.f, 0.f, 0.f};
    bf16x8 aA[2][2], bB[2][2][2];

    // prologue: tile0 {Ah0,Bh0,Bh1,Ah1}=6 + tile1 {Ah0,Bh0,Ah1}=5 loads
    SAo(As, 0, 0); SBo(Bs, 0, 0); SBo(Bs, 1, 0); SAo(As, 1, 0);
    SAo(As + A_TILE, 0, 64); SBo(Bs + B_TILE, 0, 64); SAo(As + A_TILE, 1, 64);
    asm volatile("s_waitcnt vmcnt(5)" ::: "memory");   // tile0 resident, 5 in flight
    __builtin_amdgcn_s_barrier();

    for (int T = 0; T < 16; ++T) {
        u16* Abuf = As + (T & 1) * A_TILE;
        u16* Bbuf = Bs + (T & 1) * B_TILE;
        u16* Both = Bs + ((T & 1) ^ 1) * B_TILE;
        const int k2 = T * 64 + 128;

        // ---- phase 1: (0,0)
        LAo(0); LBo(0);
        if (T < 15) SBo(Both, 1, T * 64 + 64);         // Bh1(T+1)
        __builtin_amdgcn_s_barrier();
        asm volatile("s_waitcnt lgkmcnt(0)" ::: "memory");
        __builtin_amdgcn_s_setprio(1); MMo(0, 0); __builtin_amdgcn_s_setprio(0);
        __builtin_amdgcn_s_barrier();

        // ---- phase 2: (0,1)
        LBo(1);
        if (T < 14) SAo(Abuf, 0, k2);                  // Ah0(T+2)
        __builtin_amdgcn_s_barrier();
        asm volatile("s_waitcnt lgkmcnt(0)" ::: "memory");
        __builtin_amdgcn_s_setprio(1); MMo(0, 1); __builtin_amdgcn_s_setprio(0);
        __builtin_amdgcn_s_barrier();

        // ---- phase 3: (1,0)
        LAo(1);
        if (T < 14) SBo(Bbuf, 0, k2);                  // Bh0(T+2)
        __builtin_amdgcn_s_barrier();
        asm volatile("s_waitcnt lgkmcnt(0)" ::: "memory");
        __builtin_amdgcn_s_setprio(1); MMo(1, 0); __builtin_amdgcn_s_setprio(0);
        __builtin_amdgcn_s_barrier();

        // ---- phase 4: (1,1) + counted wait
        if (T < 14) SAo(Abuf, 1, k2);                  // Ah1(T+2)
        __builtin_amdgcn_s_barrier();
        __builtin_amdgcn_s_setprio(1); MMo(1, 1); __builtin_amdgcn_s_setprio(0);
        if (T < 14)      { asm volatile("s_waitcnt vmcnt(5)" ::: "memory"); }
        else if (T < 15) { asm volatile("s_waitcnt vmcnt(0)" ::: "memory"); }
        __builtin_amdgcn_s_barrier();
    }

    // epilogue: C row = m0+wm*64+(a>>1)*32+(a&1)*16+quad*4+r, col = n0+wn*64+... [m89]
    const int r0 = quad * 4;
#pragma unroll
    for (int b2 = 0; b2 < 4; ++b2) {
        int col = n0 + wn * 64 + (b2 >> 1) * 32 + (b2 & 1) * 16 + l15;
        float bvv = bias[col];
#pragma unroll
        for (int a = 0; a < 4; ++a) {
            int row0 = m0 + wm * 64 + (a >> 1) * 32 + (a & 1) * 16 + r0;
#pragma unroll
            for (int r = 0; r < 4; ++r)
                Cout[(size_t)(row0 + r) * 1024 + col] = acc[a][b2][r] + bvv;
        }
    }
}
#undef SAo
#undef SBo
#undef LAo
#undef LBo
#undef MMo

// ---------------- MFMA causal flash attention (R5 structure) -----------------------
// One q-tile per 256-thr block; grid (64,16): x = b*16+h (same-head blocks share
// an XCD's L2), y: q-tile = 15-blockIdx.y (longest first). Wave w owns q-rows
// y*128+w*32..+31; exactly NT = 2y+2 k-tiles, all waves active every iter.
// P in registers via slot-permuted PV; K/V double-buffered; cvtpk P-pack.
// 16 waves/CU (4 blocks x 4 waves) is the TLP sweet spot — R6's 2-wave qb=4
// variant regressed 10.6 us (halved latency hiding).
__global__ __launch_bounds__(256, 4) void flash_attn_mfma(
    const u16* __restrict__ Q, const u16* __restrict__ Kq,
    const u16* __restrict__ V3, const u16* __restrict__ Pb, u16* __restrict__ O)
{
    __shared__ __align__(16) u16 Ks[2][64 * 72];     // [buf][key][d]
    __shared__ __align__(16) u16 Vs[2][64 * 72];     // [buf][d][slot]  (permuted keys)

    const int tid  = threadIdx.x;
    const int lane = tid & 63;
    const int wv   = tid >> 6;          // 0..3
    const int l15  = lane & 15;
    const int quad = lane >> 4;
    const int gg   = blockIdx.x;        // b*16 + h
    const int h    = gg & 15;
    const int b    = gg >> 4;
    const int y    = 15 - (int)blockIdx.y;   // q-tile 0..15
    const int wq0  = y * 128 + wv * 32;
    const int NT   = 2 * y + 2;

    // Q B-frags: (Q + P[s]) * 0.125*log2e, built once per block
    bf16x8 qf[2][2];
    const size_t qrowbase = (size_t)(b * SEQ) * D_MODEL + h * DK;
#pragma unroll
    for (int qb = 0; qb < 2; ++qb)
#pragma unroll
        for (int ks = 0; ks < 2; ++ks) {
            int qrow = wq0 + qb * 16 + l15;
            u16x8 qr = *(const u16x8*)(Q + qrowbase + (size_t)qrow * D_MODEL + ks * 32 + quad * 8);
            u16x8 pr = *(const u16x8*)(Pb + (size_t)qrow * D_MODEL + h * DK + ks * 32 + quad * 8);
            u16x8 o;
#pragma unroll
            for (int t = 0; t < 8; ++t)
                o[t] = f2bf((bf2f(qr[t]) + bf2f(pr[t])) * 0.180336880111120f);  // 0.125*log2e
            qf[qb][ks] = *(bf16x8*)&o;
        }

    f32x4 Oacc[2][4];
#pragma unroll
    for (int i = 0; i < 2; ++i)
#pragma unroll
        for (int jj = 0; jj < 4; ++jj) Oacc[i][jj] = f32x4{0.f, 0.f, 0.f, 0.f};
    float l_r[2] = {0.f, 0.f};

    // K staging: 256 threads, row sr = tid>>2, 32B at (tid&3)*32B
    const int sr  = tid >> 2;
    const int sc8 = (tid & 3) * 16;
    const u16* Kg = Kq + (size_t)(b * SEQ + sr) * D_MODEL + h * DK + sc8;

    // V staging: 4 uint2/thread, flat-within-tile idx = tid + 256*i (coalesced)
    const uint2* Vgp = (const uint2*)V3 + (size_t)gg * 32768 + tid;
    const int vd = tid & 63;
    int vb[4];
#pragma unroll
    for (int i = 0; i < 4; ++i) {
        int g16 = (tid >> 6) + 4 * i;
        vb[i] = (g16 >> 3) * 32 + (g16 & 3) * 8 + ((g16 >> 2) & 1) * 4;
    }

    u16x8 kr0 = *(const u16x8*)Kg;
    u16x8 kr1 = *(const u16x8*)(Kg + 8);
    uint2 vr0 = Vgp[0], vr1 = Vgp[256], vr2 = Vgp[512], vr3 = Vgp[768];

    // stage tile 0 into buf 0
    *(u16x8*)&Ks[0][sr * 72 + sc8]     = kr0;
    *(u16x8*)&Ks[0][sr * 72 + sc8 + 8] = kr1;
    *(uint2*)&Vs[0][vd * 72 + vb[0]] = vr0;
    *(uint2*)&Vs[0][vd * 72 + vb[1]] = vr1;
    *(uint2*)&Vs[0][vd * 72 + vb[2]] = vr2;
    *(uint2*)&Vs[0][vd * 72 + vb[3]] = vr3;
    __syncthreads();

    for (int kt = 0; kt < NT; ++kt) {
        const int cur = kt & 1;
        if (kt + 1 < NT) {    // prefetch next tile (lands during compute)
            const u16* Kn = Kg + (size_t)(kt + 1) * 64 * D_MODEL;
            kr0 = *(const u16x8*)Kn;
            kr1 = *(const u16x8*)(Kn + 8);
            vr0 = Vgp[(size_t)(kt + 1) * 1024];
            vr1 = Vgp[(size_t)(kt + 1) * 1024 + 256];
            vr2 = Vgp[(size_t)(kt + 1) * 1024 + 512];
            vr3 = Vgp[(size_t)(kt + 1) * 1024 + 768];
        }

        if (kt * 64 <= wq0 + 31) {   // last tile may be masked for waves 0-1
            // S^T = K-tile @ Q^T : C[key=16kb+4quad+r][q=16qb+l15]
            f32x4 sacc[4][2];
#pragma unroll
            for (int kb = 0; kb < 4; ++kb)
#pragma unroll
                for (int qb = 0; qb < 2; ++qb) sacc[kb][qb] = f32x4{0.f, 0.f, 0.f, 0.f};
            __builtin_amdgcn_s_setprio(1);
#pragma unroll
            for (int ks = 0; ks < 2; ++ks) {
                bf16x8 kf[4];
#pragma unroll
                for (int kb = 0; kb < 4; ++kb)
                    kf[kb] = *(const bf16x8*)&Ks[cur][(kb * 16 + l15) * 72 + ks * 32 + quad * 8];
#pragma unroll
                for (int kb = 0; kb < 4; ++kb)
#pragma unroll
                    for (int qb = 0; qb < 2; ++qb)
                        sacc[kb][qb] = __builtin_amdgcn_mfma_f32_16x16x32_bf16(kf[kb], qf[qb][ks], sacc[kb][qb], 0, 0, 0);
            }
            __builtin_amdgcn_s_setprio(0);

            if (kt * 64 + 63 > wq0) {   // diagonal: causal mask
#pragma unroll
                for (int kb = 0; kb < 4; ++kb) {
                    int key_g = kt * 64 + kb * 16 + quad * 4;
#pragma unroll
                    for (int qb = 0; qb < 2; ++qb) {
                        int q_g = wq0 + qb * 16 + l15;
#pragma unroll
                        for (int r = 0; r < 4; ++r)
                            if (key_g + r > q_g) sacc[kb][qb][r] = -1e30f;
                    }
                }
            }

            // fixed-max softmax: p = exp2(s); l per-lane; pf built LANE-LOCALLY
            // (slot-permuted keys: pf[qb][ks] = {p[2ks][0..3], p[2ks+1][0..3]})
            bf16x8 pf[2][2];
#pragma unroll
            for (int qb = 0; qb < 2; ++qb) {
                float s = 0.f;
                float p[4][4];
#pragma unroll
                for (int kb = 0; kb < 4; ++kb) {
                    p[kb][0] = __builtin_amdgcn_exp2f(sacc[kb][qb][0]);
                    p[kb][1] = __builtin_amdgcn_exp2f(sacc[kb][qb][1]);
                    p[kb][2] = __builtin_amdgcn_exp2f(sacc[kb][qb][2]);
                    p[kb][3] = __builtin_amdgcn_exp2f(sacc[kb][qb][3]);
                    s += (p[kb][0] + p[kb][1]) + (p[kb][2] + p[kb][3]);
                }
                l_r[qb] += s;
#pragma unroll
                for (int ks = 0; ks < 2; ++ks) {
                    union { unsigned int w[4]; bf16x8 v; } u;
                    u.w[0] = cvtpk(p[2 * ks][0],     p[2 * ks][1]);
                    u.w[1] = cvtpk(p[2 * ks][2],     p[2 * ks][3]);
                    u.w[2] = cvtpk(p[2 * ks + 1][0], p[2 * ks + 1][1]);
                    u.w[3] = cvtpk(p[2 * ks + 1][2], p[2 * ks + 1][3]);
                    pf[qb][ks] = u.v;
                }
            }

            // PV: O[q 32][d 64] += P @ V  (slot-permuted V matches pf)
            __builtin_amdgcn_s_setprio(1);
#pragma unroll
            for (int ks = 0; ks < 2; ++ks) {
                bf16x8 vf[4];
#pragma unroll
                for (int db = 0; db < 4; ++db)
                    vf[db] = *(const bf16x8*)&Vs[cur][(db * 16 + l15) * 72 + ks * 32 + quad * 8];
#pragma unroll
                for (int qb = 0; qb < 2; ++qb)
#pragma unroll
                    for (int db = 0; db < 4; ++db)
                        Oacc[qb][db] = __builtin_amdgcn_mfma_f32_16x16x32_bf16(pf[qb][ks], vf[db], Oacc[qb][db], 0, 0, 0);
            }
            __builtin_amdgcn_s_setprio(0);
        }

        if (kt + 1 < NT) {   // write next tile into other buffer
            *(u16x8*)&Ks[cur ^ 1][sr * 72 + sc8]     = kr0;
            *(u16x8*)&Ks[cur ^ 1][sr * 72 + sc8 + 8] = kr1;
            *(uint2*)&Vs[cur ^ 1][vd * 72 + vb[0]] = vr0;
            *(uint2*)&Vs[cur ^ 1][vd * 72 + vb[1]] = vr1;
            *(uint2*)&Vs[cur ^ 1][vd * 72 + vb[2]] = vr2;
            *(uint2*)&Vs[cur ^ 1][vd * 72 + vb[3]] = vr3;
        }
        __syncthreads();
    }

    // epilogue: reduce l across quads, normalize, store (C-frag rows q=quad*4+r)
    float linv[2];
#pragma unroll
    for (int qb = 0; qb < 2; ++qb) {
        float s = l_r[qb];
        s += __shfl_xor(s, 16);
        s += __shfl_xor(s, 32);
        linv[qb] = 1.f / s;
    }
#pragma unroll
    for (int qb = 0; qb < 2; ++qb)
#pragma unroll
        for (int r = 0; r < 4; ++r) {
            float li = __shfl(linv[qb], quad * 4 + r);
            size_t row = (size_t)(b * SEQ + wq0 + qb * 16 + quad * 4 + r) * D_MODEL + h * DK;
#pragma unroll
            for (int db = 0; db < 4; ++db)
                O[row + db * 16 + l15] = f2bf(Oacc[qb][db][r] * li);
        }
}

// ---------------------------------------------------------------------------
extern "C" void kernel_launch(void* const* d_in, const int* in_sizes, int n_in,
                              void* d_out, int out_size, void* d_ws, size_t ws_size,
                              hipStream_t stream) {
    const float* x  = (const float*)d_in[0];
    const float* pe = (const float*)d_in[1];
    const float* Wq = (const float*)d_in[2];  const float* bq = (const float*)d_in[3];
    const float* Wk = (const float*)d_in[4];  const float* bk = (const float*)d_in[5];
    const float* Wv = (const float*)d_in[6];  const float* bv = (const float*)d_in[7];
    const float* Wp = (const float*)d_in[8];  const float* bp = (const float*)d_in[9];
    const float* Wo = (const float*)d_in[10]; const float* bo = (const float*)d_in[11];
    float* out = (float*)d_out;
    char* ws = (char*)d_ws;

    size_t off = 0;
    u16* xb  = (u16*)(ws + off); off += (size_t)MROWS * D_MODEL * 2;   // reused as AO
    u16* peb = (u16*)(ws + off); off += (size_t)SEQ * D_MODEL * 2;
    u16* wqb = (u16*)(ws + off); off += (size_t)D_MODEL * D_MODEL * 2;
    u16* wkb = (u16*)(ws + off); off += (size_t)D_MODEL * D_MODEL * 2;
    u16* wvb = (u16*)(ws + off); off += (size_t)D_MODEL * D_MODEL * 2;
    u16* wpb = (u16*)(ws + off); off += (size_t)D_MODEL * D_MODEL * 2;
    u16* wob = (u16*)(ws + off); off += (size_t)D_MODEL * D_MODEL * 2;
    u16* Qb  = (u16*)(ws + off); off += (size_t)MROWS * D_MODEL * 2;
    u16* Kb  = (u16*)(ws + off); off += (size_t)MROWS * D_MODEL * 2;
    u16* V3b = (u16*)(ws + off); off += (size_t)MROWS * D_MODEL * 2;   // interleaved V
    u16* Pb  = (u16*)(ws + off); off += (size_t)SEQ * D_MODEL * 2;     // pos projection
    u16* AO = xb;             // attention output aliases xb (x consumed by qkv_gemm)

    convert_all<<<7680, 256, 0, stream>>>(x, pe, Wq, Wk, Wv, Wp, Wo,
                                          xb, peb, wqb, wkb, wvb, wpb, wob);

    // Q / K / V / P, 256^2 8-phase counted-vmcnt schedule, m-major-per-XCD
    qkv_gemm256<<<416, 512, 0, stream>>>(
        xb, peb, wqb, wkb, wvb, wpb, bq, bk, bv, bp, Qb, Kb, V3b, Pb);

    // 256-thr blocks, 4 waves x 32 q-rows; 1024 blocks = 4/CU, longest-first
    flash_attn_mfma<<<dim3(64, 16), 256, 0, stream>>>(Qb, Kb, V3b, Pb, AO);

    // out = AO @ Wo^T + bo  (fp32, 8-phase 256x128, exactly 256 blocks)
    gemm_out256n<<<256, 512, 0, stream>>>(AO, wob, bo, out);
}

// Round 10
// 248.077 us; speedup vs baseline: 1.0426x; 1.0426x over previous
//
#include <hip/hip_runtime.h>

#define D_MODEL 1024
#define N_HEADS 16
#define DK 64
#define BATCH 4
#define SEQ 2048
#define MROWS (BATCH * SEQ)   // 8192
#define TILE_E (256 * 64)     // u16 elems in one 256x64 bf16 LDS tile (32 KiB)

typedef float f32x4 __attribute__((ext_vector_type(4)));
typedef short bf16x8 __attribute__((ext_vector_type(8)));
typedef unsigned short u16;
typedef unsigned short u16x8 __attribute__((ext_vector_type(8)));

__device__ __forceinline__ float bf2f(u16 u) {
    union { unsigned int i; float f; } v; v.i = ((unsigned int)u) << 16; return v.f;
}
__device__ __forceinline__ u16 f2bf(float f) {
    union { float f; unsigned int i; } v; v.f = f;
    unsigned int u = v.i;
    u += 0x7fffu + ((u >> 16) & 1u);  // RNE
    return (u16)(u >> 16);
}
// pack two fp32 -> two bf16 (round-half-up) in ONE v_perm: low u16 = a, high = b
__device__ __forceinline__ unsigned int pk2(float a, float b) {
    union { float f; unsigned int i; } ua, ub; ua.f = a; ub.f = b;
    return __builtin_amdgcn_perm(ub.i + 0x8000u, ua.i + 0x8000u, 0x07060302u);
}
// pack two fp32 -> two bf16 (RNE) in one HW instr (T12)
__device__ __forceinline__ unsigned int cvtpk(float a, float b) {
    unsigned int r;
    asm("v_cvt_pk_bf16_f32 %0, %1, %2" : "=v"(r) : "v"(a), "v"(b));
    return r;
}

// async global->LDS, 16B per lane; LDS dest = wave-uniform base + lane*16
typedef unsigned int u32_as1 __attribute__((address_space(1)));
typedef unsigned int u32_as3 __attribute__((address_space(3)));
__device__ __forceinline__ void gload16(const u16* g, u16* l) {
    __builtin_amdgcn_global_load_lds((const u32_as1*)g, (u32_as3*)l, 16, 0, 0);
}

// ---------------- fused fp32 -> bf16 conversion (all 7 tensors, 8 elems/thread) ----
__global__ __launch_bounds__(256) void convert_all(
    const float* __restrict__ x, const float* __restrict__ pe,
    const float* __restrict__ w0, const float* __restrict__ w1, const float* __restrict__ w2,
    const float* __restrict__ w3, const float* __restrict__ w4,
    u16* __restrict__ xb, u16* __restrict__ pb,
    u16* __restrict__ wb0, u16* __restrict__ wb1, u16* __restrict__ wb2,
    u16* __restrict__ wb3, u16* __restrict__ wb4)
{
    int t = blockIdx.x * 256 + threadIdx.x;   // unit = 8 elems
    const float* src; u16* dst; int idx;
    if (t < 1048576)      { src = x;  dst = xb; idx = t; }
    else if (t < 1310720) { src = pe; dst = pb; idx = t - 1048576; }
    else {
        int r = t - 1310720; int w = r >> 17; idx = r & 131071;
        if      (w == 0) { src = w0; dst = wb0; }
        else if (w == 1) { src = w1; dst = wb1; }
        else if (w == 2) { src = w2; dst = wb2; }
        else if (w == 3) { src = w3; dst = wb3; }
        else             { src = w4; dst = wb4; }
    }
    const float4* p = (const float4*)src + (size_t)idx * 2;
    float4 a = p[0], b = p[1];
    u16x8 o;
    o[0] = f2bf(a.x); o[1] = f2bf(a.y); o[2] = f2bf(a.z); o[3] = f2bf(a.w);
    o[4] = f2bf(b.x); o[5] = f2bf(b.y); o[6] = f2bf(b.z); o[7] = f2bf(b.w);
    *((u16x8*)dst + idx) = o;
}

// ===========================================================================
// 256x256 / BK=64 / 8-wave / 8-phase GEMM core (T2+T3+T4+T5, m201 template).
// K = 1024 fixed (NT = 16 tiles of 64). Stage stream / counted-vmcnt design
// unchanged since round 1.
// ===========================================================================
#define SA(bufp, h, kk) do { \
    gload16(Ag + (size_t)((h) * 64) * 1024 + (kk),       (bufp) + ((h) * 64 + wv * 8) * 64); \
    gload16(Ag + (size_t)((h) * 64 + 128) * 1024 + (kk), (bufp) + ((h) * 64 + 128 + wv * 8) * 64); \
} while (0)
#define SB(bufp, h, kk) do { \
    gload16(Wg + (size_t)((h) * 32) * 1024 + (kk),       (bufp) + (wq2 * 64 + (h) * 32 + w3 * 8) * 64); \
    gload16(Wg + (size_t)((h) * 32 + 128) * 1024 + (kk), (bufp) + (128 + wq2 * 64 + (h) * 32 + w3 * 8) * 64); \
} while (0)
#define LOAD_A(mh) \
    _Pragma("unroll") \
    for (int mi = 0; mi < 4; ++mi) { \
        aA[mi][0] = *(const bf16x8*)&Abuf[aoff0 + ((mh) * 64 + mi * 16) * 64]; \
        aA[mi][1] = *(const bf16x8*)&Abuf[aoff1 + ((mh) * 64 + mi * 16) * 64]; \
    }
#define LOAD_B(nh) \
    _Pragma("unroll") \
    for (int ni = 0; ni < 2; ++ni) { \
        bB[nh][ni][0] = *(const bf16x8*)&Bbuf[boff0 + ((nh) * 32 + ni * 16) * 64]; \
        bB[nh][ni][1] = *(const bf16x8*)&Bbuf[boff1 + ((nh) * 32 + ni * 16) * 64]; \
    }
#define MFMA16(mh, nh) \
    _Pragma("unroll") \
    for (int ks = 0; ks < 2; ++ks) \
        _Pragma("unroll") \
        for (int mi = 0; mi < 4; ++mi) \
            _Pragma("unroll") \
            for (int ni = 0; ni < 2; ++ni) \
                acc[(mh) * 4 + mi][(nh) * 2 + ni] = __builtin_amdgcn_mfma_f32_16x16x32_bf16( \
                    aA[mi][ks], bB[nh][ni][ks], acc[(mh) * 4 + mi][(nh) * 2 + ni], 0, 0, 0);

__device__ __forceinline__ void gemm256_loop(
    const u16* __restrict__ Ag, const u16* __restrict__ Wg,
    u16* AsBase, u16* BsBase, int wv,
    int aoff0, int aoff1, int boff0, int boff1, f32x4 (&acc)[8][4])
{
    const int wq2 = wv >> 2, w3 = wv & 3;
    bf16x8 aA[4][2], bB[2][2][2];

    // prologue: tile0 {Ah0,Bh0,Bh1,Ah1} + tile1 {Ah0,Bh0,Ah1}  (14 loads)
    SA(AsBase, 0, 0); SB(BsBase, 0, 0); SB(BsBase, 1, 0); SA(AsBase, 1, 0);
    SA(AsBase + TILE_E, 0, 64); SB(BsBase + TILE_E, 0, 64); SA(AsBase + TILE_E, 1, 64);
    asm volatile("s_waitcnt vmcnt(6)" ::: "memory");   // tile0 resident, 3 halves in flight
    __builtin_amdgcn_s_barrier();

    for (int T = 0; T < 16; ++T) {
        u16* Abuf = AsBase + (T & 1) * TILE_E;
        u16* Bbuf = BsBase + (T & 1) * TILE_E;
        u16* Both = BsBase + ((T & 1) ^ 1) * TILE_E;
        const int k2 = T * 64 + 128;

        // ---- phase 1: (mh=0, nh=0)
        LOAD_A(0); LOAD_B(0);
        if (T < 15) SB(Both, 1, T * 64 + 64);          // Bh1(T+1)
        __builtin_amdgcn_s_barrier();
        asm volatile("s_waitcnt lgkmcnt(0)" ::: "memory");
        __builtin_amdgcn_s_setprio(1); MFMA16(0, 0); __builtin_amdgcn_s_setprio(0);
        __builtin_amdgcn_s_barrier();

        // ---- phase 2: (0,1)
        LOAD_B(1);
        if (T < 14) SA(Abuf, 0, k2);                   // Ah0(T+2) over consumed region
        __builtin_amdgcn_s_barrier();
        asm volatile("s_waitcnt lgkmcnt(0)" ::: "memory");
        __builtin_amdgcn_s_setprio(1); MFMA16(0, 1); __builtin_amdgcn_s_setprio(0);
        __builtin_amdgcn_s_barrier();

        // ---- phase 3: (1,0)
        LOAD_A(1);
        if (T < 14) SB(Bbuf, 0, k2);                   // Bh0(T+2)
        __builtin_amdgcn_s_barrier();
        asm volatile("s_waitcnt lgkmcnt(0)" ::: "memory");
        __builtin_amdgcn_s_setprio(1); MFMA16(1, 0); __builtin_amdgcn_s_setprio(0);
        __builtin_amdgcn_s_barrier();

        // ---- phase 4: (1,1), counted wait for next tile (never vmcnt 0 mid-loop)
        if (T < 14) SA(Abuf, 1, k2);                   // Ah1(T+2)
        __builtin_amdgcn_s_barrier();
        __builtin_amdgcn_s_setprio(1); MFMA16(1, 1); __builtin_amdgcn_s_setprio(0);
        if (T < 14)      { asm volatile("s_waitcnt vmcnt(6)" ::: "memory"); }
        else if (T < 15) { asm volatile("s_waitcnt vmcnt(0)" ::: "memory"); }
        __builtin_amdgcn_s_barrier();
    }
}

// ---------------- fused QKVP GEMM: 416 blocks --------------------------------------
// m-major-per-XCD mapping (R9): XCD x owns m-tiles {4x..4x+3} for all 12
// (chunk,n) groups + 4 P-tiles -> co-resident A working set 2 MB (fits L2);
// FETCH_SIZE 110 -> 51 MB measured. Epilogue: Q/K/P LDS-bounce full-line stores.
__global__ __launch_bounds__(512, 1) void qkv_gemm256(
    const u16* __restrict__ xb, const u16* __restrict__ peb,
    const u16* __restrict__ wqb, const u16* __restrict__ wkb,
    const u16* __restrict__ wvb, const u16* __restrict__ wpb,
    const float* __restrict__ bq, const float* __restrict__ bk,
    const float* __restrict__ bv, const float* __restrict__ bp,
    u16* __restrict__ Qb, u16* __restrict__ Kb, u16* __restrict__ V3,
    u16* __restrict__ Pb)
{
    __shared__ __align__(16) u16 SH[4 * TILE_E];   // 128 KiB: As | Bs, reused by epilogue
    u16* As = SH;
    u16* Bs = SH + 2 * TILE_E;

    const int tid  = threadIdx.x;
    const int lane = tid & 63;
    const int wv   = tid >> 6;     // 0..7
    const int l15  = lane & 15;
    const int quad = lane >> 4;
    const int wm = wv >> 2, wn = wv & 3;

    // m-major-per-XCD mapping (bijective: 8 XCD x 52 idx = 416)
    const int xcd = blockIdx.x & 7;
    const int idx = blockIdx.x >> 3;          // 0..51
    int chunk, m0, n0;
    if (idx < 48) {
        int g = idx >> 2;                     // 0..11 = (chunk, nb)
        chunk = g >> 2; n0 = (g & 3) * 256;
        m0 = (xcd * 4 + (idx & 3)) * 256;     // XCD-contiguous m
    } else {
        int p = xcd * 4 + (idx - 48);         // 0..31
        chunk = 3; m0 = (p & 7) * 256; n0 = (p >> 3) * 256;
    }

    const u16* Abase = (chunk == 3) ? peb : xb;
    const u16* Wbase = (chunk == 0) ? wqb : ((chunk == 1) ? wkb : ((chunk == 2) ? wvb : wpb));

    // staging: per-thread global source with pre-applied column swizzle
    const int trow = tid >> 3;                             // 0..63
    const int swz  = ((tid & 7) ^ (trow & 7)) * 8;
    const u16* Ag = Abase + (size_t)(m0 + trow) * 1024 + swz;
    const u16* Wg = Wbase + (size_t)(n0 + (wv >> 2) * 64 + (trow & 31)) * 1024 + swz;

    // ds_read offsets with matching swizzle (row&7 == l15&7 for all frag rows)
    const int x7 = l15 & 7;
    const int aoff0 = (wm * 128 + l15) * 64 + ((quad    ) ^ x7) * 8;
    const int aoff1 = (wm * 128 + l15) * 64 + ((quad + 4) ^ x7) * 8;
    const int boff0 = (wn * 64 + l15) * 64 + ((quad    ) ^ x7) * 8;
    const int boff1 = (wn * 64 + l15) * 64 + ((quad + 4) ^ x7) * 8;

    f32x4 acc[8][4];
#pragma unroll
    for (int i = 0; i < 8; ++i)
#pragma unroll
        for (int j = 0; j < 4; ++j) acc[i][j] = f32x4{0.f, 0.f, 0.f, 0.f};

    gemm256_loop(Ag, Wg, As, Bs, wv, aoff0, aoff1, boff0, boff1, acc);

    // epilogue [m89 layout: C row = quad*4+r (+16m), col = l15 (+16n)]
    const float* bias = (chunk == 0) ? bq : ((chunk == 1) ? bk : ((chunk == 2) ? bv : bp));
    const int r0 = quad * 4;
    if (chunk == 2) {                            // V -> interleaved layout (128B/instr already)
#pragma unroll
        for (int n = 0; n < 4; ++n) {
            int col = n0 + wn * 64 + n * 16 + l15;
            float bvv = bias[col];
#pragma unroll
            for (int m = 0; m < 8; ++m) {
                int row0 = m0 + wm * 128 + m * 16 + r0;
                int hh = col >> 6, d = col & 63;
                int bb = row0 >> 11, sl = row0 & 2047;
                union { u16 h[4]; uint2 v; } pk;
#pragma unroll
                for (int r = 0; r < 4; ++r) pk.h[r] = f2bf(acc[m][n][r] + bvv);
                *((uint2*)V3 + ((size_t)(bb * 16 + hh) * 512 + (sl >> 2)) * 64 + d) = pk.v;
            }
        }
    } else {                                     // Q/K/P: LDS bounce -> full-line stores
        u16* dst = (chunk == 0) ? Qb : ((chunk == 1) ? Kb : Pb);
#pragma unroll
        for (int p = 0; p < 2; ++p) {
            __syncthreads();                     // prior pass reads / K-loop reads done
            if (wm == p) {                       // 4 waves own rows p*128..p*128+127
#pragma unroll
                for (int n = 0; n < 4; ++n) {
                    int colL = wn * 64 + n * 16 + l15;
                    float bvv = bias[n0 + colL];
#pragma unroll
                    for (int m = 0; m < 8; ++m) {
#pragma unroll
                        for (int r = 0; r < 4; ++r)
                            SH[(m * 16 + r0 + r) * 264 + colL] = f2bf(acc[m][n][r] + bvv);
                    }
                }
            }
            __syncthreads();
            // 512 threads, 8 lanes/row: each instr = 16 rows x 128B full lines
            const int rbase = m0 + p * 128;
#pragma unroll
            for (int s = 0; s < 2; ++s) {
                int rowL = (tid >> 3) + s * 64;
#pragma unroll
                for (int i = 0; i < 4; ++i) {
                    int cc = (tid & 7) + i * 8;          // 16B chunk 0..31
                    *(u16x8*)(dst + (size_t)(rbase + rowL) * 1024 + n0 + cc * 8) =
                        *(const u16x8*)&SH[rowL * 264 + cc * 8];
                }
            }
        }
    }
}

#undef SA
#undef SB
#undef LOAD_A
#undef LOAD_B
#undef MFMA16

// ---------------- output GEMM: out[8192,1024] = AO @ Wo^T + bo (fp32 out) ----------
// 8-phase counted-vmcnt core, 256m x 128n tile -> EXACTLY 256 blocks
// (one machine-wave, zero tail). 8 waves as 4m x 2n (wave-tile 64x64, acc[4][4]).
// THIS ROUND: LDS-bounce fp32 epilogue (same pattern as qkv R1 fix) -> each
// 128B output line fully written by coalesced float4 stores (kills the
// partial-line write overshoot of the scalar m89-order stores).
#define A_TILE (256 * 64)
#define B_TILE (128 * 64)
#define SAo(bufp, h, kk) do { \
    gload16(Ag + (size_t)((h) * 32) * 1024 + (kk),     (bufp) + (adst + (h) * 32) * 64); \
    gload16(Ag + (size_t)((h) * 32 + 8) * 1024 + (kk), (bufp) + (adst + (h) * 32 + 8) * 64); \
} while (0)
#define SBo(bufp, nh, kk) \
    gload16(Wg + (size_t)((nh) * 32) * 1024 + (kk), (bufp) + (bdst + (nh) * 32) * 64)
#define LAo(mh) \
    _Pragma("unroll") \
    for (int mi = 0; mi < 2; ++mi) { \
        aA[mi][0] = *(const bf16x8*)&Abuf[aoff0 + ((mh) * 32 + mi * 16) * 64]; \
        aA[mi][1] = *(const bf16x8*)&Abuf[aoff1 + ((mh) * 32 + mi * 16) * 64]; \
    }
#define LBo(nh) \
    _Pragma("unroll") \
    for (int ni = 0; ni < 2; ++ni) { \
        bB[nh][ni][0] = *(const bf16x8*)&Bbuf[boff0 + ((nh) * 32 + ni * 16) * 64]; \
        bB[nh][ni][1] = *(const bf16x8*)&Bbuf[boff1 + ((nh) * 32 + ni * 16) * 64]; \
    }
#define MMo(mh, nh) \
    _Pragma("unroll") \
    for (int ks = 0; ks < 2; ++ks) \
        _Pragma("unroll") \
        for (int mi = 0; mi < 2; ++mi) \
            _Pragma("unroll") \
            for (int ni = 0; ni < 2; ++ni) \
                acc[(mh) * 2 + mi][(nh) * 2 + ni] = __builtin_amdgcn_mfma_f32_16x16x32_bf16( \
                    aA[mi][ks], bB[nh][ni][ks], acc[(mh) * 2 + mi][(nh) * 2 + ni], 0, 0, 0);

__global__ __launch_bounds__(512, 2) void gemm_out256n(
    const u16* __restrict__ A, const u16* __restrict__ W,
    const float* __restrict__ bias, float* __restrict__ Cout)
{
    // fused 96 KiB block: As | Bs during K-loop, fp32 bounce buffer in epilogue
    __shared__ __align__(16) u16 SH2[2 * A_TILE + 2 * B_TILE];
    u16* As = SH2;
    u16* Bs = SH2 + 2 * A_TILE;

    const int tid  = threadIdx.x;
    const int lane = tid & 63;
    const int wv   = tid >> 6;
    const int l15  = lane & 15;
    const int quad = lane >> 4;
    const int wm = wv >> 1, wn = wv & 1;   // 4m x 2n wave grid

    int wg = (blockIdx.x & 7) * 32 + (blockIdx.x >> 3);   // bijective XCD swizzle
    const int m0 = (wg >> 3) * 256;
    const int n0 = (wg & 7) * 128;

    // staging: per-thread global source with pre-applied column swizzle
    const int swz    = ((tid & 7) ^ ((tid >> 3) & 7)) * 8;
    const int arow_t = (wv >> 1) * 64 + (wv & 1) * 16 + (lane >> 3);
    const int brow_t = (wv >> 2) * 64 + (wv & 3) * 8 + (lane >> 3);
    const u16* Ag = A + (size_t)(m0 + arow_t) * 1024 + swz;
    const u16* Wg = W + (size_t)(n0 + brow_t) * 1024 + swz;
    const int adst = (wv >> 1) * 64 + (wv & 1) * 16;   // + h*32 (+8 for 2nd call)
    const int bdst = (wv >> 2) * 64 + (wv & 3) * 8;    // + nh*32

    const int x7 = l15 & 7;
    const int aoff0 = (wm * 64 + l15) * 64 + ((quad    ) ^ x7) * 8;
    const int aoff1 = (wm * 64 + l15) * 64 + ((quad + 4) ^ x7) * 8;
    const int boff0 = (wn * 64 + l15) * 64 + ((quad    ) ^ x7) * 8;
    const int boff1 = (wn * 64 + l15) * 64 + ((quad + 4) ^ x7) * 8;

    f32x4 acc[4][4];
#pragma unroll
    for (int i = 0; i < 4; ++i)
#pragma unroll
        for (int j = 0; j < 4; ++j) acc[i][j] = f32x4{0.f, 0.f, 0.f, 0.f};
    bf16x8 aA[2][2], bB[2][2][2];

    // prologue: tile0 {Ah0,Bh0,Bh1,Ah1}=6 + tile1 {Ah0,Bh0,Ah1}=5 loads
    SAo(As, 0, 0); SBo(Bs, 0, 0); SBo(Bs, 1, 0); SAo(As, 1, 0);
    SAo(As + A_TILE, 0, 64); SBo(Bs + B_TILE, 0, 64); SAo(As + A_TILE, 1, 64);
    asm volatile("s_waitcnt vmcnt(5)" ::: "memory");   // tile0 resident, 5 in flight
    __builtin_amdgcn_s_barrier();

    for (int T = 0; T < 16; ++T) {
        u16* Abuf = As + (T & 1) * A_TILE;
        u16* Bbuf = Bs + (T & 1) * B_TILE;
        u16* Both = Bs + ((T & 1) ^ 1) * B_TILE;
        const int k2 = T * 64 + 128;

        // ---- phase 1: (0,0)
        LAo(0); LBo(0);
        if (T < 15) SBo(Both, 1, T * 64 + 64);         // Bh1(T+1)
        __builtin_amdgcn_s_barrier();
        asm volatile("s_waitcnt lgkmcnt(0)" ::: "memory");
        __builtin_amdgcn_s_setprio(1); MMo(0, 0); __builtin_amdgcn_s_setprio(0);
        __builtin_amdgcn_s_barrier();

        // ---- phase 2: (0,1)
        LBo(1);
        if (T < 14) SAo(Abuf, 0, k2);                  // Ah0(T+2)
        __builtin_amdgcn_s_barrier();
        asm volatile("s_waitcnt lgkmcnt(0)" ::: "memory");
        __builtin_amdgcn_s_setprio(1); MMo(0, 1); __builtin_amdgcn_s_setprio(0);
        __builtin_amdgcn_s_barrier();

        // ---- phase 3: (1,0)
        LAo(1);
        if (T < 14) SBo(Bbuf, 0, k2);                  // Bh0(T+2)
        __builtin_amdgcn_s_barrier();
        asm volatile("s_waitcnt lgkmcnt(0)" ::: "memory");
        __builtin_amdgcn_s_setprio(1); MMo(1, 0); __builtin_amdgcn_s_setprio(0);
        __builtin_amdgcn_s_barrier();

        // ---- phase 4: (1,1) + counted wait
        if (T < 14) SAo(Abuf, 1, k2);                  // Ah1(T+2)
        __builtin_amdgcn_s_barrier();
        __builtin_amdgcn_s_setprio(1); MMo(1, 1); __builtin_amdgcn_s_setprio(0);
        if (T < 14)      { asm volatile("s_waitcnt vmcnt(5)" ::: "memory"); }
        else if (T < 15) { asm volatile("s_waitcnt vmcnt(0)" ::: "memory"); }
        __builtin_amdgcn_s_barrier();
    }

    // epilogue: LDS bounce -> full-line float4 stores  [m89 frag layout]
    // pass p: waves wm in {2p,2p+1} own rows p*128..p*128+127; pad 132 breaks
    // the quad-row bank aliasing on the write side.
    float* Cs = (float*)SH2;                  // 128*132*4 = 67.6 KB <= 96 KiB
    const int r0 = quad * 4;
#pragma unroll
    for (int p = 0; p < 2; ++p) {
        __syncthreads();                      // K-loop LDS reads / prior pass done
        if ((wm >> 1) == p) {
#pragma unroll
            for (int b2 = 0; b2 < 4; ++b2) {
                int colL = wn * 64 + (b2 >> 1) * 32 + (b2 & 1) * 16 + l15;
                float bvv = bias[n0 + colL];
#pragma unroll
                for (int a = 0; a < 4; ++a) {
                    int rowL = (wm & 1) * 64 + (a >> 1) * 32 + (a & 1) * 16 + r0;
#pragma unroll
                    for (int r = 0; r < 4; ++r)
                        Cs[(rowL + r) * 132 + colL] = acc[a][b2][r] + bvv;
                }
            }
        }
        __syncthreads();
        // 512 threads: 4 threads/row x 8 float4 -> 128 rows fully written,
        // 64B-contiguous per instruction (write-combine friendly)
        const int rbase = m0 + p * 128;
        const int rowL  = tid >> 2;
        const int cq    = (tid & 3) * 4;
#pragma unroll
        for (int j = 0; j < 8; ++j) {
            int colL = cq + j * 16;
            *(float4*)(Cout + (size_t)(rbase + rowL) * 1024 + n0 + colL) =
                *(const float4*)&Cs[rowL * 132 + colL];
        }
    }
}
#undef SAo
#undef SBo
#undef LAo
#undef LBo
#undef MMo

// ---------------- MFMA causal flash attention (R5 structure) -----------------------
// One q-tile per 256-thr block; grid (64,16): x = b*16+h (same-head blocks share
// an XCD's L2), y: q-tile = 15-blockIdx.y (longest first). Wave w owns q-rows
// y*128+w*32..+31; exactly NT = 2y+2 k-tiles, all waves active every iter.
// P in registers via slot-permuted PV; K/V double-buffered; cvtpk P-pack.
// 16 waves/CU (4 blocks x 4 waves) is the TLP sweet spot — R6's 2-wave qb=4
// variant regressed 10.6 us (halved latency hiding).
__global__ __launch_bounds__(256, 4) void flash_attn_mfma(
    const u16* __restrict__ Q, const u16* __restrict__ Kq,
    const u16* __restrict__ V3, const u16* __restrict__ Pb, u16* __restrict__ O)
{
    __shared__ __align__(16) u16 Ks[2][64 * 72];     // [buf][key][d]
    __shared__ __align__(16) u16 Vs[2][64 * 72];     // [buf][d][slot]  (permuted keys)

    const int tid  = threadIdx.x;
    const int lane = tid & 63;
    const int wv   = tid >> 6;          // 0..3
    const int l15  = lane & 15;
    const int quad = lane >> 4;
    const int gg   = blockIdx.x;        // b*16 + h
    const int h    = gg & 15;
    const int b    = gg >> 4;
    const int y    = 15 - (int)blockIdx.y;   // q-tile 0..15
    const int wq0  = y * 128 + wv * 32;
    const int NT   = 2 * y + 2;

    // Q B-frags: (Q + P[s]) * 0.125*log2e, built once per block
    bf16x8 qf[2][2];
    const size_t qrowbase = (size_t)(b * SEQ) * D_MODEL + h * DK;
#pragma unroll
    for (int qb = 0; qb < 2; ++qb)
#pragma unroll
        for (int ks = 0; ks < 2; ++ks) {
            int qrow = wq0 + qb * 16 + l15;
            u16x8 qr = *(const u16x8*)(Q + qrowbase + (size_t)qrow * D_MODEL + ks * 32 + quad * 8);
            u16x8 pr = *(const u16x8*)(Pb + (size_t)qrow * D_MODEL + h * DK + ks * 32 + quad * 8);
            u16x8 o;
#pragma unroll
            for (int t = 0; t < 8; ++t)
                o[t] = f2bf((bf2f(qr[t]) + bf2f(pr[t])) * 0.180336880111120f);  // 0.125*log2e
            qf[qb][ks] = *(bf16x8*)&o;
        }

    f32x4 Oacc[2][4];
#pragma unroll
    for (int i = 0; i < 2; ++i)
#pragma unroll
        for (int jj = 0; jj < 4; ++jj) Oacc[i][jj] = f32x4{0.f, 0.f, 0.f, 0.f};
    float l_r[2] = {0.f, 0.f};

    // K staging: 256 threads, row sr = tid>>2, 32B at (tid&3)*32B
    const int sr  = tid >> 2;
    const int sc8 = (tid & 3) * 16;
    const u16* Kg = Kq + (size_t)(b * SEQ + sr) * D_MODEL + h * DK + sc8;

    // V staging: 4 uint2/thread, flat-within-tile idx = tid + 256*i (coalesced)
    const uint2* Vgp = (const uint2*)V3 + (size_t)gg * 32768 + tid;
    const int vd = tid & 63;
    int vb[4];
#pragma unroll
    for (int i = 0; i < 4; ++i) {
        int g16 = (tid >> 6) + 4 * i;
        vb[i] = (g16 >> 3) * 32 + (g16 & 3) * 8 + ((g16 >> 2) & 1) * 4;
    }

    u16x8 kr0 = *(const u16x8*)Kg;
    u16x8 kr1 = *(const u16x8*)(Kg + 8);
    uint2 vr0 = Vgp[0], vr1 = Vgp[256], vr2 = Vgp[512], vr3 = Vgp[768];

    // stage tile 0 into buf 0
    *(u16x8*)&Ks[0][sr * 72 + sc8]     = kr0;
    *(u16x8*)&Ks[0][sr * 72 + sc8 + 8] = kr1;
    *(uint2*)&Vs[0][vd * 72 + vb[0]] = vr0;
    *(uint2*)&Vs[0][vd * 72 + vb[1]] = vr1;
    *(uint2*)&Vs[0][vd * 72 + vb[2]] = vr2;
    *(uint2*)&Vs[0][vd * 72 + vb[3]] = vr3;
    __syncthreads();

    for (int kt = 0; kt < NT; ++kt) {
        const int cur = kt & 1;
        if (kt + 1 < NT) {    // prefetch next tile (lands during compute)
            const u16* Kn = Kg + (size_t)(kt + 1) * 64 * D_MODEL;
            kr0 = *(const u16x8*)Kn;
            kr1 = *(const u16x8*)(Kn + 8);
            vr0 = Vgp[(size_t)(kt + 1) * 1024];
            vr1 = Vgp[(size_t)(kt + 1) * 1024 + 256];
            vr2 = Vgp[(size_t)(kt + 1) * 1024 + 512];
            vr3 = Vgp[(size_t)(kt + 1) * 1024 + 768];
        }

        if (kt * 64 <= wq0 + 31) {   // last tile may be masked for waves 0-1
            // S^T = K-tile @ Q^T : C[key=16kb+4quad+r][q=16qb+l15]
            f32x4 sacc[4][2];
#pragma unroll
            for (int kb = 0; kb < 4; ++kb)
#pragma unroll
                for (int qb = 0; qb < 2; ++qb) sacc[kb][qb] = f32x4{0.f, 0.f, 0.f, 0.f};
            __builtin_amdgcn_s_setprio(1);
#pragma unroll
            for (int ks = 0; ks < 2; ++ks) {
                bf16x8 kf[4];
#pragma unroll
                for (int kb = 0; kb < 4; ++kb)
                    kf[kb] = *(const bf16x8*)&Ks[cur][(kb * 16 + l15) * 72 + ks * 32 + quad * 8];
#pragma unroll
                for (int kb = 0; kb < 4; ++kb)
#pragma unroll
                    for (int qb = 0; qb < 2; ++qb)
                        sacc[kb][qb] = __builtin_amdgcn_mfma_f32_16x16x32_bf16(kf[kb], qf[qb][ks], sacc[kb][qb], 0, 0, 0);
            }
            __builtin_amdgcn_s_setprio(0);

            if (kt * 64 + 63 > wq0) {   // diagonal: causal mask
#pragma unroll
                for (int kb = 0; kb < 4; ++kb) {
                    int key_g = kt * 64 + kb * 16 + quad * 4;
#pragma unroll
                    for (int qb = 0; qb < 2; ++qb) {
                        int q_g = wq0 + qb * 16 + l15;
#pragma unroll
                        for (int r = 0; r < 4; ++r)
                            if (key_g + r > q_g) sacc[kb][qb][r] = -1e30f;
                    }
                }
            }

            // fixed-max softmax: p = exp2(s); l per-lane; pf built LANE-LOCALLY
            // (slot-permuted keys: pf[qb][ks] = {p[2ks][0..3], p[2ks+1][0..3]})
            bf16x8 pf[2][2];
#pragma unroll
            for (int qb = 0; qb < 2; ++qb) {
                float s = 0.f;
                float p[4][4];
#pragma unroll
                for (int kb = 0; kb < 4; ++kb) {
                    p[kb][0] = __builtin_amdgcn_exp2f(sacc[kb][qb][0]);
                    p[kb][1] = __builtin_amdgcn_exp2f(sacc[kb][qb][1]);
                    p[kb][2] = __builtin_amdgcn_exp2f(sacc[kb][qb][2]);
                    p[kb][3] = __builtin_amdgcn_exp2f(sacc[kb][qb][3]);
                    s += (p[kb][0] + p[kb][1]) + (p[kb][2] + p[kb][3]);
                }
                l_r[qb] += s;
#pragma unroll
                for (int ks = 0; ks < 2; ++ks) {
                    union { unsigned int w[4]; bf16x8 v; } u;
                    u.w[0] = cvtpk(p[2 * ks][0],     p[2 * ks][1]);
                    u.w[1] = cvtpk(p[2 * ks][2],     p[2 * ks][3]);
                    u.w[2] = cvtpk(p[2 * ks + 1][0], p[2 * ks + 1][1]);
                    u.w[3] = cvtpk(p[2 * ks + 1][2], p[2 * ks + 1][3]);
                    pf[qb][ks] = u.v;
                }
            }

            // PV: O[q 32][d 64] += P @ V  (slot-permuted V matches pf)
            __builtin_amdgcn_s_setprio(1);
#pragma unroll
            for (int ks = 0; ks < 2; ++ks) {
                bf16x8 vf[4];
#pragma unroll
                for (int db = 0; db < 4; ++db)
                    vf[db] = *(const bf16x8*)&Vs[cur][(db * 16 + l15) * 72 + ks * 32 + quad * 8];
#pragma unroll
                for (int qb = 0; qb < 2; ++qb)
#pragma unroll
                    for (int db = 0; db < 4; ++db)
                        Oacc[qb][db] = __builtin_amdgcn_mfma_f32_16x16x32_bf16(pf[qb][ks], vf[db], Oacc[qb][db], 0, 0, 0);
            }
            __builtin_amdgcn_s_setprio(0);
        }

        if (kt + 1 < NT) {   // write next tile into other buffer
            *(u16x8*)&Ks[cur ^ 1][sr * 72 + sc8]     = kr0;
            *(u16x8*)&Ks[cur ^ 1][sr * 72 + sc8 + 8] = kr1;
            *(uint2*)&Vs[cur ^ 1][vd * 72 + vb[0]] = vr0;
            *(uint2*)&Vs[cur ^ 1][vd * 72 + vb[1]] = vr1;
            *(uint2*)&Vs[cur ^ 1][vd * 72 + vb[2]] = vr2;
            *(uint2*)&Vs[cur ^ 1][vd * 72 + vb[3]] = vr3;
        }
        __syncthreads();
    }

    // epilogue: reduce l across quads, normalize, store (C-frag rows q=quad*4+r)
    float linv[2];
#pragma unroll
    for (int qb = 0; qb < 2; ++qb) {
        float s = l_r[qb];
        s += __shfl_xor(s, 16);
        s += __shfl_xor(s, 32);
        linv[qb] = 1.f / s;
    }
#pragma unroll
    for (int qb = 0; qb < 2; ++qb)
#pragma unroll
        for (int r = 0; r < 4; ++r) {
            float li = __shfl(linv[qb], quad * 4 + r);
            size_t row = (size_t)(b * SEQ + wq0 + qb * 16 + quad * 4 + r) * D_MODEL + h * DK;
#pragma unroll
            for (int db = 0; db < 4; ++db)
                O[row + db * 16 + l15] = f2bf(Oacc[qb][db][r] * li);
        }
}

// ---------------------------------------------------------------------------
extern "C" void kernel_launch(void* const* d_in, const int* in_sizes, int n_in,
                              void* d_out, int out_size, void* d_ws, size_t ws_size,
                              hipStream_t stream) {
    const float* x  = (const float*)d_in[0];
    const float* pe = (const float*)d_in[1];
    const float* Wq = (const float*)d_in[2];  const float* bq = (const float*)d_in[3];
    const float* Wk = (const float*)d_in[4];  const float* bk = (const float*)d_in[5];
    const float* Wv = (const float*)d_in[6];  const float* bv = (const float*)d_in[7];
    const float* Wp = (const float*)d_in[8];  const float* bp = (const float*)d_in[9];
    const float* Wo = (const float*)d_in[10]; const float* bo = (const float*)d_in[11];
    float* out = (float*)d_out;
    char* ws = (char*)d_ws;

    size_t off = 0;
    u16* xb  = (u16*)(ws + off); off += (size_t)MROWS * D_MODEL * 2;   // reused as AO
    u16* peb = (u16*)(ws + off); off += (size_t)SEQ * D_MODEL * 2;
    u16* wqb = (u16*)(ws + off); off += (size_t)D_MODEL * D_MODEL * 2;
    u16* wkb = (u16*)(ws + off); off += (size_t)D_MODEL * D_MODEL * 2;
    u16* wvb = (u16*)(ws + off); off += (size_t)D_MODEL * D_MODEL * 2;
    u16* wpb = (u16*)(ws + off); off += (size_t)D_MODEL * D_MODEL * 2;
    u16* wob = (u16*)(ws + off); off += (size_t)D_MODEL * D_MODEL * 2;
    u16* Qb  = (u16*)(ws + off); off += (size_t)MROWS * D_MODEL * 2;
    u16* Kb  = (u16*)(ws + off); off += (size_t)MROWS * D_MODEL * 2;
    u16* V3b = (u16*)(ws + off); off += (size_t)MROWS * D_MODEL * 2;   // interleaved V
    u16* Pb  = (u16*)(ws + off); off += (size_t)SEQ * D_MODEL * 2;     // pos projection
    u16* AO = xb;             // attention output aliases xb (x consumed by qkv_gemm)

    convert_all<<<7680, 256, 0, stream>>>(x, pe, Wq, Wk, Wv, Wp, Wo,
                                          xb, peb, wqb, wkb, wvb, wpb, wob);

    // Q / K / V / P, 256^2 8-phase counted-vmcnt schedule, m-major-per-XCD
    qkv_gemm256<<<416, 512, 0, stream>>>(
        xb, peb, wqb, wkb, wvb, wpb, bq, bk, bv, bp, Qb, Kb, V3b, Pb);

    // 256-thr blocks, 4 waves x 32 q-rows; 1024 blocks = 4/CU, longest-first
    flash_attn_mfma<<<dim3(64, 16), 256, 0, stream>>>(Qb, Kb, V3b, Pb, AO);

    // out = AO @ Wo^T + bo  (fp32, 8-phase 256x128, LDS-bounce epilogue)
    gemm_out256n<<<256, 512, 0, stream>>>(AO, wob, bo, out);
}